// Round 10
// baseline (208.354 us; speedup 1.0000x reference)
//
#include <hip/hip_runtime.h>
#include <math.h>

#define BB   16384
#define OBS  512
#define NE   16
#define ACTD 256
#define TK   4

// ---------------- ws layout (proven ≥ 91 MB) ----------------
#define WS_ROWLIST_OFF  ((size_t)64)
#define WS_PROBLIST_OFF (WS_ROWLIST_OFF + (size_t)NE * BB * 4)
#define WS_SLOT_OFF     (WS_PROBLIST_OFF + (size_t)NE * BB * 4)
#define WS_XBF_OFF      (WS_SLOT_OFF + (size_t)NE * BB * 4)
#define WS_WM_OFF       (WS_XBF_OFF + (size_t)BB * OBS * 2)
#define WS_WL_OFF       (WS_WM_OFF + (size_t)NE * ACTD * OBS * 2)
#define WS_PART_OFF     (WS_WL_OFF + (size_t)NE * ACTD * OBS * 2)
#define WS_NEEDED_A2    (WS_PART_OFF + (size_t)2 * BB * TK * ACTD * 2)

typedef __attribute__((ext_vector_type(8))) short short8;
typedef __attribute__((ext_vector_type(4))) float floatx4;

__device__ __forceinline__ ushort f2bf(float f) {
    union { float f; unsigned u; } v; v.f = f;
    unsigned r = v.u + 0x7fffu + ((v.u >> 16) & 1u);
    return (ushort)(r >> 16);
}
__device__ __forceinline__ float bf2f(ushort u) {
    union { unsigned u; float f; } v; v.u = ((unsigned)u) << 16;
    return v.f;
}
// -5 + 3.5*(tanh(v)+1) == -5 + 7/(1+exp(-2v))
__device__ __forceinline__ float lstd_act(float v) {
    return -5.f + 7.f * __builtin_amdgcn_rcpf(1.f + __expf(-2.f * v));
}

// -------------------------------------------------------------------------
// Router v3 (unchanged, proven): routing + x->bf16 + fused weight cvt.
// -------------------------------------------------------------------------
__global__ __launch_bounds__(256) void router_kernel(
    const float* __restrict__ x, const float* __restrict__ rw,
    const float* __restrict__ rb,
    int* __restrict__ counts, int* __restrict__ rowlist,
    float* __restrict__ problist, int* __restrict__ slot_of,
    ushort* __restrict__ xbf,
    const float* __restrict__ mwf, const float* __restrict__ lwf,
    ushort* __restrict__ wmbf, ushort* __restrict__ wlbf, int do_aux)
{
    __shared__ float wlds[NE * OBS];
    __shared__ int   lcnt[NE], lbase[NE];
    __shared__ int   s_e[64], s_lpos[64];
    __shared__ float s_p[64];

    const float4* rw4 = (const float4*)rw;
    float4* wl4 = (float4*)wlds;
    #pragma unroll
    for (int i = 0; i < 8; ++i) wl4[threadIdx.x + 256 * i] = rw4[threadIdx.x + 256 * i];
    if (threadIdx.x < NE) lcnt[threadIdx.x] = 0;
    __syncthreads();

    const int wave = threadIdx.x >> 6;
    const int lane = threadIdx.x & 63;
    const int q    = lane >> 4;
    const int i16  = lane & 15;
    const int row  = blockIdx.x * 16 + wave * 4 + q;

    const float4* xr = (const float4*)(x + (size_t)row * OBS);
    float4 xv[8];
    #pragma unroll
    for (int s = 0; s < 8; ++s) xv[s] = xr[s * 16 + i16];

    if (do_aux) {
        ushort4* xo = (ushort4*)(xbf + (size_t)row * OBS);
        #pragma unroll
        for (int s = 0; s < 8; ++s) {
            ushort4 o;
            o.x = f2bf(xv[s].x); o.y = f2bf(xv[s].y);
            o.z = f2bf(xv[s].z); o.w = f2bf(xv[s].w);
            xo[s * 16 + i16] = o;
        }
    }

    float p[NE];
    float m = -1e30f;
    #pragma unroll
    for (int e = 0; e < NE; ++e) {
        const float4* wep = (const float4*)(wlds + e * OBS);
        float d = 0.f;
        #pragma unroll
        for (int s = 0; s < 8; ++s) {
            float4 wv = wep[s * 16 + i16];
            d += xv[s].x * wv.x + xv[s].y * wv.y + xv[s].z * wv.z + xv[s].w * wv.w;
        }
        d += __shfl_xor(d, 1, 64);
        d += __shfl_xor(d, 2, 64);
        d += __shfl_xor(d, 4, 64);
        d += __shfl_xor(d, 8, 64);
        d += rb[e];
        p[e] = d;
        m = fmaxf(m, d);
    }
    float s = 0.f;
    #pragma unroll
    for (int e = 0; e < NE; ++e) { p[e] = __expf(p[e] - m); s += p[e]; }
    const float inv = 1.f / s;
    #pragma unroll
    for (int e = 0; e < NE; ++e) p[e] *= inv;

    int   sel_e[TK];
    float sel_p[TK];
    #pragma unroll
    for (int k = 0; k < TK; ++k) {
        float best = -1.f; int be = 0;
        #pragma unroll
        for (int e = 0; e < NE; ++e)
            if (p[e] > best) { best = p[e]; be = e; }
        sel_e[k] = be; sel_p[k] = best;
        #pragma unroll
        for (int e = 0; e < NE; ++e)
            if (e == be) p[e] = -2.f;
    }
    if (i16 < TK) {
        const int e = sel_e[i16];
        const int lpos = atomicAdd(&lcnt[e], 1);
        const int sid = (wave * 4 + q) * 4 + i16;
        s_e[sid] = e; s_p[sid] = sel_p[i16]; s_lpos[sid] = lpos;
    }
    __syncthreads();
    if (threadIdx.x < NE)
        lbase[threadIdx.x] = atomicAdd(&counts[threadIdx.x], lcnt[threadIdx.x]);
    __syncthreads();
    if (threadIdx.x < 64) {
        const int sid = threadIdx.x;
        const int e   = s_e[sid];
        const int pos = lbase[e] + s_lpos[sid];
        const int grow = blockIdx.x * 16 + (sid >> 2);
        rowlist[e * BB + pos]  = grow;
        problist[e * BB + pos] = s_p[sid];
        if (do_aux) slot_of[e * BB + pos] = grow * TK + (sid & 3);
    }

    // ---- fused weight conversion (both tensors) ----
    if (do_aux) {
        const int gid = blockIdx.x * 256 + threadIdx.x;     // 0..262143
        const float4* m4 = (const float4*)mwf;
        const float4* l4 = (const float4*)lwf;
        ushort4* mo = (ushort4*)wmbf;
        ushort4* lo = (ushort4*)wlbf;
        #pragma unroll
        for (int j = 0; j < 2; ++j) {
            const int idx = gid + 262144 * j;               // wn4 = 524288
            float4 a = m4[idx];
            ushort4 oa;
            oa.x = f2bf(a.x); oa.y = f2bf(a.y); oa.z = f2bf(a.z); oa.w = f2bf(a.w);
            mo[idx] = oa;
            float4 b = l4[idx];
            ushort4 ob;
            ob.x = f2bf(b.x); ob.y = f2bf(b.y); ob.z = f2bf(b.z); ob.w = f2bf(b.w);
            lo[idx] = ob;
        }
    }
}

// -------------------------------------------------------------------------
// Expert-grouped bf16 MFMA GEMM, 128x128 tile, 4 waves of 64x64 — r7
// geometry + COUNTED-VMCNT DOUBLE BUFFER (guide T4, m218-verified):
//   per K-step: issue next tile's 8 global_load_lds; s_waitcnt vmcnt(8)
//   (current tile's 8 loads — issued LAST iter — are the only older VMEM,
//   so they are retired; in-order retirement per m135); raw s_barrier;
//   ds_read+MFMA current; raw s_barrier (all waves done reading before
//   anyone restages this buffer next iter). Loads never drain to 0 in the
//   main loop — HBM/L2 latency hides under the 32-MFMA compute window
//   instead of being exposed at every barrier (r3's dbuf drained to 0 at
//   every __syncthreads and lost; this is the counted version).
// LDS 64 KB (2 x 32 KB) -> 2 blocks/CU; reg cap was 4 blocks (64 VGPR +
// 64 AGPR unified = 128/wave), so we trade 2 blocks of TLP for real ILP.
// sched_barrier(0) fences both barriers against compiler motion.
// Grid/remap/swizzle/epilogue unchanged from r9.
// -------------------------------------------------------------------------
__global__ __launch_bounds__(256, 2) void moe_gemm_128(
    const ushort* __restrict__ xbf,
    const ushort* __restrict__ wmean, const ushort* __restrict__ wlstd,
    const float* __restrict__ mean_b, const float* __restrict__ lstd_b,
    const int* __restrict__ counts, const int* __restrict__ rowlist,
    const float* __restrict__ problist, const int* __restrict__ slot_of,
    ushort* __restrict__ partial)
{
    const int flat = blockIdx.x + 528 * blockIdx.y;
    const int virt = (flat & 7) * 264 + (flat >> 3);
    const int zz   = virt & 3;
    const int gt   = virt >> 2;          // compact tile id 0..527

    // decode (expert, tile0) from compact tile id via counts prefix scan
    int e = -1, tile0 = 0, cnt = 0, tsum = 0;
    #pragma unroll
    for (int ee = 0; ee < NE; ++ee) {
        const int ce = counts[ee];
        const int nt = (ce + 127) >> 7;
        if (e < 0 && gt < tsum + nt) { e = ee; tile0 = (gt - tsum) * 128; cnt = ce; }
        tsum += nt;
    }
    if (e < 0) return;

    const int which = zz >> 1;
    const int ctile = (zz & 1) * 128;
    const ushort* W   = (which ? wlstd : wmean) + (size_t)e * ACTD * OBS;
    const float* bias = (which ? lstd_b : mean_b) + e * ACTD + ctile;
    ushort* Pp = partial + (size_t)which * BB * TK * ACTD;

    __shared__ __align__(16) ushort xls[2][128 * 64];   // 2 x 16 KB
    __shared__ __align__(16) ushort wls[2][128 * 64];   // 2 x 16 KB

    const int tid = threadIdx.x;
    const int l   = tid & 63;
    const int w   = tid >> 6;

    const int c_sw = (l & 7) ^ (l >> 3);
    // x windows: wave w stages windows {4w..4w+3} (8 tile-rows each)
    const ushort* xp[4];
    #pragma unroll
    for (int i = 0; i < 4; ++i) {
        const int lrow = 32 * w + 8 * i + (l >> 3);
        const int pos  = tile0 + lrow;
        const int grow = (pos < cnt) ? rowlist[e * BB + pos] : rowlist[e * BB + tile0];
        xp[i] = xbf + (size_t)grow * OBS + c_sw * 8;
    }
    // W windows: wave w stages windows {4w..4w+3} (8 cols each)
    const ushort* wp[4];
    #pragma unroll
    for (int j = 0; j < 4; ++j) {
        const int col = ctile + 32 * w + 8 * j + (l >> 3);
        wp[j] = W + (size_t)col * OBS + c_sw * 8;
    }

    const int wm  = (w >> 1) * 64;   // row-half of 128
    const int wn  = (w & 1) * 64;    // col-half of 128
    const int rlo = l & 15;
    const int q   = l >> 4;
    const int r7  = rlo & 7;

    floatx4 acc[4][4];
    #pragma unroll
    for (int mi = 0; mi < 4; ++mi)
        #pragma unroll
        for (int ni = 0; ni < 4; ++ni)
            acc[mi][ni] = (floatx4){0.f, 0.f, 0.f, 0.f};

#define STAGE(B, KT)                                                          \
    do {                                                                      \
        _Pragma("unroll")                                                     \
        for (int i = 0; i < 4; ++i)                                           \
            __builtin_amdgcn_global_load_lds(                                 \
                (const __attribute__((address_space(1))) unsigned int*)(xp[i] + (KT)), \
                (__attribute__((address_space(3))) unsigned int*)(&xls[B][(4 * w + i) * 512]), \
                16, 0, 0);                                                    \
        _Pragma("unroll")                                                     \
        for (int j = 0; j < 4; ++j)                                           \
            __builtin_amdgcn_global_load_lds(                                 \
                (const __attribute__((address_space(1))) unsigned int*)(wp[j] + (KT)), \
                (__attribute__((address_space(3))) unsigned int*)(&wls[B][(4 * w + j) * 512]), \
                16, 0, 0);                                                    \
    } while (0)

    STAGE(0, 0);                          // prologue: 8 loads in flight

    #pragma unroll
    for (int kt_i = 0; kt_i < 8; ++kt_i) {
        const int b = kt_i & 1;
        if (kt_i < 7) {
            STAGE(b ^ 1, (kt_i + 1) * 64);            // +8 loads (newest)
            asm volatile("s_waitcnt vmcnt(8)" ::: "memory");  // buf b's 8 retired
        } else {
            asm volatile("s_waitcnt vmcnt(0)" ::: "memory");  // final drain
        }
        __builtin_amdgcn_s_barrier();     // all waves' buf-b data landed
        __builtin_amdgcn_sched_barrier(0);

        #pragma unroll
        for (int ks = 0; ks < 2; ++ks) {
            const int ch = (4 * ks + q) ^ r7;
            short8 af[4], bfr[4];
            #pragma unroll
            for (int mi = 0; mi < 4; ++mi)
                af[mi] = *(const short8*)(&xls[b][(wm + mi * 16 + rlo) * 64 + ch * 8]);
            #pragma unroll
            for (int ni = 0; ni < 4; ++ni)
                bfr[ni] = *(const short8*)(&wls[b][(wn + ni * 16 + rlo) * 64 + ch * 8]);
            #pragma unroll
            for (int mi = 0; mi < 4; ++mi)
                #pragma unroll
                for (int ni = 0; ni < 4; ++ni)
                    acc[mi][ni] = __builtin_amdgcn_mfma_f32_16x16x32_bf16(
                        af[mi], bfr[ni], acc[mi][ni], 0, 0, 0);
        }
        __builtin_amdgcn_sched_barrier(0);
        asm volatile("s_waitcnt lgkmcnt(0)" ::: "memory");  // my ds_reads done
        __builtin_amdgcn_s_barrier();     // all waves done reading buf b
        __builtin_amdgcn_sched_barrier(0);
    }
#undef STAGE

    // epilogue: slot/prob loaded directly (16 lanes share each address ->
    // broadcast load, L2-hot)
    #pragma unroll
    for (int mi = 0; mi < 4; ++mi) {
        #pragma unroll
        for (int r = 0; r < 4; ++r) {
            const int lrow = wm + mi * 16 + q * 4 + r;
            const int pos  = tile0 + lrow;
            if (pos >= cnt) continue;
            const int slot = slot_of[e * BB + pos];
            const float pw = problist[e * BB + pos];
            ushort* orow = Pp + (size_t)slot * ACTD + ctile + wn + rlo;
            #pragma unroll
            for (int ni = 0; ni < 4; ++ni)
                orow[ni * 16] = f2bf(pw * (acc[mi][ni][r] + bias[wn + ni * 16 + rlo]));
        }
    }
}

// -------------------------------------------------------------------------
// Combine: out[r] = sum_k partial[r*4+k]; ushort8 (b128) loads.
// Thread handles 8 cols; grid = BB*32/256 = 2048 blocks.
// -------------------------------------------------------------------------
__global__ __launch_bounds__(256) void combine_kernel(
    const ushort* __restrict__ partial, float* __restrict__ out)
{
    const int t  = blockIdx.x * 256 + threadIdx.x;
    const int r  = t >> 5;
    const int c8 = (t & 31) * 8;
    const ushort* Pm = partial;
    const ushort* Pl = partial + (size_t)BB * TK * ACTD;

    float sm[8] = {}, sl[8] = {};
    #pragma unroll
    for (int k = 0; k < TK; ++k) {
        const size_t off = (size_t)(r * TK + k) * ACTD + c8;
        short8 vm = *(const short8*)(Pm + off);
        short8 vl = *(const short8*)(Pl + off);
        #pragma unroll
        for (int j = 0; j < 8; ++j) {
            sm[j] += bf2f((ushort)vm[j]);
            sl[j] += bf2f((ushort)vl[j]);
        }
    }
    float4 mo0 = make_float4(sm[0], sm[1], sm[2], sm[3]);
    float4 mo1 = make_float4(sm[4], sm[5], sm[6], sm[7]);
    float4 lo0 = make_float4(lstd_act(sl[0]), lstd_act(sl[1]), lstd_act(sl[2]), lstd_act(sl[3]));
    float4 lo1 = make_float4(lstd_act(sl[4]), lstd_act(sl[5]), lstd_act(sl[6]), lstd_act(sl[7]));
    float* om = out + (size_t)r * ACTD + c8;
    float* ol = out + (size_t)BB * ACTD + (size_t)r * ACTD + c8;
    *(float4*)(om)     = mo0;
    *(float4*)(om + 4) = mo1;
    *(float4*)(ol)     = lo0;
    *(float4*)(ol + 4) = lo1;
}

// -------------------------------------------------------------------------
// Tier B: fp32 expert-grouped GEMM (round-1, proven fallback).
// -------------------------------------------------------------------------
__global__ __launch_bounds__(256) void moe_gemm_f32(
    const float* __restrict__ x,
    const float* __restrict__ mean_w, const float* __restrict__ mean_b,
    const float* __restrict__ lstd_w, const float* __restrict__ lstd_b,
    const int* __restrict__ counts, const int* __restrict__ rowlist,
    const float* __restrict__ problist, float* __restrict__ out)
{
    const int e = blockIdx.y;
    const int cnt = counts[e];
    const int tile0 = blockIdx.x * 32;
    if (tile0 >= cnt) return;

    const int zz    = blockIdx.z;
    const int which = zz >> 1;
    const int ctile = (zz & 1) * 128;
    const float* W    = (which ? lstd_w : mean_w) + (size_t)e * ACTD * OBS;
    const float* bias = (which ? lstd_b : mean_b) + e * ACTD;
    float* outp = out + (size_t)which * BB * ACTD;

    __shared__ float xls[32][32];
    __shared__ float wls[32][128];

    const int sr  = threadIdx.x >> 3;
    const int skq = threadIdx.x & 7;
    int stage_row = -1;
    {
        const int pos = tile0 + sr;
        if (pos < cnt) stage_row = rowlist[e * BB + pos];
    }

    const int r0 = (threadIdx.x >> 5) << 2;
    const int c0 = (threadIdx.x & 31) << 2;

    float acc[4][4] = {};

    for (int kt = 0; kt < OBS; kt += 32) {
        __syncthreads();
        {
            float4 v = make_float4(0.f, 0.f, 0.f, 0.f);
            if (stage_row >= 0)
                v = *(const float4*)(x + (size_t)stage_row * OBS + kt + skq * 4);
            xls[skq * 4 + 0][sr] = v.x;
            xls[skq * 4 + 1][sr] = v.y;
            xls[skq * 4 + 2][sr] = v.z;
            xls[skq * 4 + 3][sr] = v.w;
        }
        #pragma unroll
        for (int j = 0; j < 4; ++j) {
            const int i  = threadIdx.x + 256 * j;
            const int c  = i >> 3;
            const int kq = i & 7;
            float4 v = *(const float4*)(W + (size_t)(ctile + c) * OBS + kt + kq * 4);
            wls[kq * 4 + 0][c] = v.x;
            wls[kq * 4 + 1][c] = v.y;
            wls[kq * 4 + 2][c] = v.z;
            wls[kq * 4 + 3][c] = v.w;
        }
        __syncthreads();

        #pragma unroll
        for (int k = 0; k < 32; ++k) {
            const float4 xa = *(const float4*)&xls[k][r0];
            const float4 wb = *(const float4*)&wls[k][c0];
            const float xv[4] = { xa.x, xa.y, xa.z, xa.w };
            const float wv[4] = { wb.x, wb.y, wb.z, wb.w };
            #pragma unroll
            for (int i = 0; i < 4; ++i)
                #pragma unroll
                for (int j = 0; j < 4; ++j)
                    acc[i][j] = fmaf(xv[i], wv[j], acc[i][j]);
        }
    }

    #pragma unroll
    for (int i = 0; i < 4; ++i) {
        const int pos = tile0 + r0 + i;
        if (pos >= cnt) break;
        const int grow = rowlist[e * BB + pos];
        const float pw = problist[e * BB + pos];
        float* orow = outp + (size_t)grow * ACTD + ctile + c0;
        #pragma unroll
        for (int j = 0; j < 4; ++j)
            atomicAdd(&orow[j], pw * (acc[i][j] + bias[ctile + c0 + j]));
    }
}

__global__ __launch_bounds__(256) void tanh_ep(float* __restrict__ out)
{
    const int i = blockIdx.x * 256 + threadIdx.x;
    float4* p = (float4*)(out + (size_t)BB * ACTD);
    float4 v = p[i];
    v.x = -5.f + 3.5f * (tanhf(v.x) + 1.f);
    v.y = -5.f + 3.5f * (tanhf(v.y) + 1.f);
    v.z = -5.f + 3.5f * (tanhf(v.z) + 1.f);
    v.w = -5.f + 3.5f * (tanhf(v.w) + 1.f);
    p[i] = v;
}

extern "C" void kernel_launch(void* const* d_in, const int* in_sizes, int n_in,
                              void* d_out, int out_size, void* d_ws, size_t ws_size,
                              hipStream_t stream)
{
    const float* x        = (const float*)d_in[0];
    const float* router_w = (const float*)d_in[1];
    const float* router_b = (const float*)d_in[2];
    const float* mean_w   = (const float*)d_in[3];
    const float* mean_b   = (const float*)d_in[4];
    const float* lstd_w   = (const float*)d_in[5];
    const float* lstd_b   = (const float*)d_in[6];

    float* out = (float*)d_out;
    int*    counts   = (int*)d_ws;
    int*    rowlist  = (int*)((char*)d_ws + WS_ROWLIST_OFF);
    float*  problist = (float*)((char*)d_ws + WS_PROBLIST_OFF);
    int*    slot_of  = (int*)((char*)d_ws + WS_SLOT_OFF);
    ushort* xbf      = (ushort*)((char*)d_ws + WS_XBF_OFF);
    ushort* wmbf     = (ushort*)((char*)d_ws + WS_WM_OFF);
    ushort* wlbf     = (ushort*)((char*)d_ws + WS_WL_OFF);
    ushort* partial  = (ushort*)((char*)d_ws + WS_PART_OFF);

    const bool tierA2 = (ws_size >= WS_NEEDED_A2);

    if (tierA2) {
        hipMemsetAsync(d_ws, 0, 64, stream);   // zero the 16 counters

        router_kernel<<<BB / 16, 256, 0, stream>>>(x, router_w, router_b,
                                                   counts, rowlist, problist,
                                                   slot_of, xbf,
                                                   mean_w, lstd_w, wmbf, wlbf, 1);

        dim3 grid(528, 4);
        moe_gemm_128<<<grid, 256, 0, stream>>>(xbf, wmbf, wlbf, mean_b, lstd_b,
                                               counts, rowlist, problist,
                                               slot_of, partial);
        combine_kernel<<<BB * 32 / 256, 256, 0, stream>>>(partial, out);
    } else {
        hipMemsetAsync(d_ws, 0, 64, stream);
        hipMemsetAsync(d_out, 0, (size_t)out_size * sizeof(float), stream);
        router_kernel<<<BB / 16, 256, 0, stream>>>(x, router_w, router_b,
                                                   counts, rowlist, problist,
                                                   (int*)nullptr, (ushort*)nullptr,
                                                   (const float*)nullptr,
                                                   (const float*)nullptr,
                                                   (ushort*)nullptr, (ushort*)nullptr, 0);
        dim3 grid(BB / 32, NE, 4);
        moe_gemm_f32<<<grid, 256, 0, stream>>>(x, mean_w, mean_b, lstd_w, lstd_b,
                                               counts, rowlist, problist, out);
        tanh_ep<<<(BB * ACTD / 4) / 256, 256, 0, stream>>>(out);
    }
}

// Round 11
// 191.383 us; speedup vs baseline: 1.0887x; 1.0887x over previous
//
#include <hip/hip_runtime.h>
#include <math.h>

#define BB   16384
#define OBS  512
#define NE   16
#define ACTD 256
#define TK   4

// ---------------- ws layout (proven ≥ 91 MB) ----------------
#define WS_ROWLIST_OFF  ((size_t)64)
#define WS_PROBLIST_OFF (WS_ROWLIST_OFF + (size_t)NE * BB * 4)
#define WS_SLOT_OFF     (WS_PROBLIST_OFF + (size_t)NE * BB * 4)
#define WS_XBF_OFF      (WS_SLOT_OFF + (size_t)NE * BB * 4)
#define WS_WM_OFF       (WS_XBF_OFF + (size_t)BB * OBS * 2)
#define WS_WL_OFF       (WS_WM_OFF + (size_t)NE * ACTD * OBS * 2)
#define WS_PART_OFF     (WS_WL_OFF + (size_t)NE * ACTD * OBS * 2)
#define WS_NEEDED_A2    (WS_PART_OFF + (size_t)2 * BB * TK * ACTD * 2)

typedef __attribute__((ext_vector_type(8))) short short8;
typedef __attribute__((ext_vector_type(4))) float floatx4;

__device__ __forceinline__ ushort f2bf(float f) {
    union { float f; unsigned u; } v; v.f = f;
    unsigned r = v.u + 0x7fffu + ((v.u >> 16) & 1u);
    return (ushort)(r >> 16);
}
__device__ __forceinline__ float bf2f(ushort u) {
    union { unsigned u; float f; } v; v.u = ((unsigned)u) << 16;
    return v.f;
}
// -5 + 3.5*(tanh(v)+1) == -5 + 7/(1+exp(-2v))
__device__ __forceinline__ float lstd_act(float v) {
    return -5.f + 7.f * __builtin_amdgcn_rcpf(1.f + __expf(-2.f * v));
}

// -------------------------------------------------------------------------
// Router v4: 32 rows/block in TWO passes over the LDS-resident router
// weights (same per-row math as proven v3). Halves the block count
// (1024->512) and the global atomic count (16384->8192 same-line atomics
// on counts[0..15]) — the per-block tail waits on same-line L2 atomic
// serialization, so contention halving shortens every block's critical
// path. Fused weight cvt redistributed: 4 float4 per tensor per thread.
// -------------------------------------------------------------------------
__global__ __launch_bounds__(256) void router_kernel(
    const float* __restrict__ x, const float* __restrict__ rw,
    const float* __restrict__ rb,
    int* __restrict__ counts, int* __restrict__ rowlist,
    float* __restrict__ problist, int* __restrict__ slot_of,
    ushort* __restrict__ xbf,
    const float* __restrict__ mwf, const float* __restrict__ lwf,
    ushort* __restrict__ wmbf, ushort* __restrict__ wlbf, int do_aux)
{
    __shared__ float wlds[NE * OBS];
    __shared__ int   lcnt[NE], lbase[NE];
    __shared__ int   s_e[128], s_lpos[128];
    __shared__ float s_p[128];

    const float4* rw4 = (const float4*)rw;
    float4* wl4 = (float4*)wlds;
    #pragma unroll
    for (int i = 0; i < 8; ++i) wl4[threadIdx.x + 256 * i] = rw4[threadIdx.x + 256 * i];
    if (threadIdx.x < NE) lcnt[threadIdx.x] = 0;
    __syncthreads();

    const int wave = threadIdx.x >> 6;
    const int lane = threadIdx.x & 63;
    const int q    = lane >> 4;
    const int i16  = lane & 15;

    #pragma unroll
    for (int p = 0; p < 2; ++p) {
        const int row = blockIdx.x * 32 + p * 16 + wave * 4 + q;

        const float4* xr = (const float4*)(x + (size_t)row * OBS);
        float4 xv[8];
        #pragma unroll
        for (int s = 0; s < 8; ++s) xv[s] = xr[s * 16 + i16];

        if (do_aux) {
            ushort4* xo = (ushort4*)(xbf + (size_t)row * OBS);
            #pragma unroll
            for (int s = 0; s < 8; ++s) {
                ushort4 o;
                o.x = f2bf(xv[s].x); o.y = f2bf(xv[s].y);
                o.z = f2bf(xv[s].z); o.w = f2bf(xv[s].w);
                xo[s * 16 + i16] = o;
            }
        }

        float pv[NE];
        float m = -1e30f;
        #pragma unroll
        for (int e = 0; e < NE; ++e) {
            const float4* wep = (const float4*)(wlds + e * OBS);
            float d = 0.f;
            #pragma unroll
            for (int s = 0; s < 8; ++s) {
                float4 wv = wep[s * 16 + i16];
                d += xv[s].x * wv.x + xv[s].y * wv.y + xv[s].z * wv.z + xv[s].w * wv.w;
            }
            d += __shfl_xor(d, 1, 64);
            d += __shfl_xor(d, 2, 64);
            d += __shfl_xor(d, 4, 64);
            d += __shfl_xor(d, 8, 64);
            d += rb[e];
            pv[e] = d;
            m = fmaxf(m, d);
        }
        float s = 0.f;
        #pragma unroll
        for (int e = 0; e < NE; ++e) { pv[e] = __expf(pv[e] - m); s += pv[e]; }
        const float inv = 1.f / s;
        #pragma unroll
        for (int e = 0; e < NE; ++e) pv[e] *= inv;

        int   sel_e[TK];
        float sel_p[TK];
        #pragma unroll
        for (int k = 0; k < TK; ++k) {
            float best = -1.f; int be = 0;
            #pragma unroll
            for (int e = 0; e < NE; ++e)
                if (pv[e] > best) { best = pv[e]; be = e; }
            sel_e[k] = be; sel_p[k] = best;
            #pragma unroll
            for (int e = 0; e < NE; ++e)
                if (e == be) pv[e] = -2.f;
        }
        if (i16 < TK) {
            const int e = sel_e[i16];
            const int lpos = atomicAdd(&lcnt[e], 1);
            const int sid = p * 64 + (wave * 4 + q) * 4 + i16;
            s_e[sid] = e; s_p[sid] = sel_p[i16]; s_lpos[sid] = lpos;
        }
    }
    __syncthreads();
    if (threadIdx.x < NE)
        lbase[threadIdx.x] = atomicAdd(&counts[threadIdx.x], lcnt[threadIdx.x]);
    __syncthreads();
    if (threadIdx.x < 128) {
        const int sid   = threadIdx.x;
        const int e     = s_e[sid];
        const int pos   = lbase[e] + s_lpos[sid];
        const int p     = sid >> 6;
        const int local = sid & 63;
        const int grow  = blockIdx.x * 32 + p * 16 + (local >> 2);
        rowlist[e * BB + pos]  = grow;
        problist[e * BB + pos] = s_p[sid];
        if (do_aux) slot_of[e * BB + pos] = grow * TK + (local & 3);
    }

    // ---- fused weight conversion (both tensors, 4 float4 each) ----
    if (do_aux) {
        const int gid = blockIdx.x * 256 + threadIdx.x;     // 0..131071
        const float4* m4 = (const float4*)mwf;
        const float4* l4 = (const float4*)lwf;
        ushort4* mo = (ushort4*)wmbf;
        ushort4* lo = (ushort4*)wlbf;
        #pragma unroll
        for (int j = 0; j < 4; ++j) {
            const int idx = gid + 131072 * j;               // wn4 = 524288
            float4 a = m4[idx];
            ushort4 oa;
            oa.x = f2bf(a.x); oa.y = f2bf(a.y); oa.z = f2bf(a.z); oa.w = f2bf(a.w);
            mo[idx] = oa;
            float4 b = l4[idx];
            ushort4 ob;
            ob.x = f2bf(b.x); ob.y = f2bf(b.y); ob.z = f2bf(b.z); ob.w = f2bf(b.w);
            lo[idx] = ob;
        }
    }
}

// -------------------------------------------------------------------------
// Expert-grouped bf16 MFMA GEMM — EXACT round-7 structure (63.6 us proven):
// 128x128 tile, 4 waves of 64x64, single-buffer 33 KB LDS, 4 blocks/CU
// (reg-capped: 64 VGPR + 64 acc AGPR = 128/wave), compact tile space,
// XCD remap, conflict-free XOR swizzle, idx/probs LDS staging.
// r3/r5/r8/r10 all proved: at 8 K-steps/block, never trade co-resident
// blocks for per-block pipelining. This geometry is the local optimum.
// -------------------------------------------------------------------------
__global__ __launch_bounds__(256, 4) void moe_gemm_128(
    const ushort* __restrict__ xbf,
    const ushort* __restrict__ wmean, const ushort* __restrict__ wlstd,
    const float* __restrict__ mean_b, const float* __restrict__ lstd_b,
    const int* __restrict__ counts, const int* __restrict__ rowlist,
    const float* __restrict__ problist, const int* __restrict__ slot_of,
    ushort* __restrict__ partial)
{
    const int flat = blockIdx.x + 528 * blockIdx.y;
    const int virt = (flat & 7) * 264 + (flat >> 3);
    const int zz   = virt & 3;
    const int gt   = virt >> 2;          // compact tile id 0..527

    // decode (expert, tile0) from compact tile id via counts prefix scan
    int e = -1, tile0 = 0, cnt = 0, tsum = 0;
    #pragma unroll
    for (int ee = 0; ee < NE; ++ee) {
        const int ce = counts[ee];
        const int nt = (ce + 127) >> 7;
        if (e < 0 && gt < tsum + nt) { e = ee; tile0 = (gt - tsum) * 128; cnt = ce; }
        tsum += nt;
    }
    if (e < 0) return;

    const int which = zz >> 1;
    const int ctile = (zz & 1) * 128;
    const ushort* W   = (which ? wlstd : wmean) + (size_t)e * ACTD * OBS;
    const float* bias = (which ? lstd_b : mean_b) + e * ACTD + ctile;
    ushort* Pp = partial + (size_t)which * BB * TK * ACTD;

    __shared__ __align__(16) ushort xls[128 * 64];   // 16 KB: 16 windows
    __shared__ __align__(16) ushort wls[128 * 64];   // 16 KB: 16 windows
    __shared__ int   idx_l[128];
    __shared__ float probs_l[128];

    const int tid = threadIdx.x;
    const int l   = tid & 63;
    const int w   = tid >> 6;

    if (tid < 128) {
        const int pos = tile0 + tid;
        const bool v = pos < cnt;
        probs_l[tid] = v ? problist[e * BB + pos] : 0.f;
        idx_l[tid]   = v ? slot_of[e * BB + pos] : -1;
    }

    const int c_sw = (l & 7) ^ (l >> 3);
    // x windows: wave w stages windows {4w..4w+3} (8 tile-rows each)
    const ushort* xp[4];
    #pragma unroll
    for (int i = 0; i < 4; ++i) {
        const int lrow = 32 * w + 8 * i + (l >> 3);
        const int pos  = tile0 + lrow;
        const int grow = (pos < cnt) ? rowlist[e * BB + pos] : rowlist[e * BB + tile0];
        xp[i] = xbf + (size_t)grow * OBS + c_sw * 8;
    }
    // W windows: wave w stages windows {4w..4w+3} (8 cols each)
    const ushort* wp[4];
    #pragma unroll
    for (int j = 0; j < 4; ++j) {
        const int col = ctile + 32 * w + 8 * j + (l >> 3);
        wp[j] = W + (size_t)col * OBS + c_sw * 8;
    }

    const int wm  = (w >> 1) * 64;   // row-half of 128
    const int wn  = (w & 1) * 64;    // col-half of 128
    const int rlo = l & 15;
    const int q   = l >> 4;
    const int r7  = rlo & 7;

    floatx4 acc[4][4];
    #pragma unroll
    for (int mi = 0; mi < 4; ++mi)
        #pragma unroll
        for (int ni = 0; ni < 4; ++ni)
            acc[mi][ni] = (floatx4){0.f, 0.f, 0.f, 0.f};

    for (int kt = 0; kt < OBS; kt += 64) {
        __syncthreads();
        #pragma unroll
        for (int i = 0; i < 4; ++i)
            __builtin_amdgcn_global_load_lds(
                (const __attribute__((address_space(1))) unsigned int*)(xp[i] + kt),
                (__attribute__((address_space(3))) unsigned int*)(xls + (4 * w + i) * 512),
                16, 0, 0);
        #pragma unroll
        for (int j = 0; j < 4; ++j)
            __builtin_amdgcn_global_load_lds(
                (const __attribute__((address_space(1))) unsigned int*)(wp[j] + kt),
                (__attribute__((address_space(3))) unsigned int*)(wls + (4 * w + j) * 512),
                16, 0, 0);
        __syncthreads();

        #pragma unroll
        for (int ks = 0; ks < 2; ++ks) {
            const int ch = (4 * ks + q) ^ r7;
            short8 af[4], bfr[4];
            #pragma unroll
            for (int mi = 0; mi < 4; ++mi)
                af[mi] = *(const short8*)(xls + (wm + mi * 16 + rlo) * 64 + ch * 8);
            #pragma unroll
            for (int ni = 0; ni < 4; ++ni)
                bfr[ni] = *(const short8*)(wls + (wn + ni * 16 + rlo) * 64 + ch * 8);
            #pragma unroll
            for (int mi = 0; mi < 4; ++mi)
                #pragma unroll
                for (int ni = 0; ni < 4; ++ni)
                    acc[mi][ni] = __builtin_amdgcn_mfma_f32_16x16x32_bf16(
                        af[mi], bfr[ni], acc[mi][ni], 0, 0, 0);
        }
    }

    #pragma unroll
    for (int mi = 0; mi < 4; ++mi) {
        #pragma unroll
        for (int r = 0; r < 4; ++r) {
            const int lrow = wm + mi * 16 + q * 4 + r;
            const int slot = idx_l[lrow];
            if (slot < 0) continue;
            const float pw = probs_l[lrow];
            ushort* orow = Pp + (size_t)slot * ACTD + ctile + wn + rlo;
            #pragma unroll
            for (int ni = 0; ni < 4; ++ni)
                orow[ni * 16] = f2bf(pw * (acc[mi][ni][r] + bias[wn + ni * 16 + rlo]));
        }
    }
}

// -------------------------------------------------------------------------
// Combine: out[r] = sum_k partial[r*4+k]; ushort8 (b128) loads.
// Thread handles 8 cols; grid = BB*32/256 = 2048 blocks.
// -------------------------------------------------------------------------
__global__ __launch_bounds__(256) void combine_kernel(
    const ushort* __restrict__ partial, float* __restrict__ out)
{
    const int t  = blockIdx.x * 256 + threadIdx.x;
    const int r  = t >> 5;
    const int c8 = (t & 31) * 8;
    const ushort* Pm = partial;
    const ushort* Pl = partial + (size_t)BB * TK * ACTD;

    float sm[8] = {}, sl[8] = {};
    #pragma unroll
    for (int k = 0; k < TK; ++k) {
        const size_t off = (size_t)(r * TK + k) * ACTD + c8;
        short8 vm = *(const short8*)(Pm + off);
        short8 vl = *(const short8*)(Pl + off);
        #pragma unroll
        for (int j = 0; j < 8; ++j) {
            sm[j] += bf2f((ushort)vm[j]);
            sl[j] += bf2f((ushort)vl[j]);
        }
    }
    float4 mo0 = make_float4(sm[0], sm[1], sm[2], sm[3]);
    float4 mo1 = make_float4(sm[4], sm[5], sm[6], sm[7]);
    float4 lo0 = make_float4(lstd_act(sl[0]), lstd_act(sl[1]), lstd_act(sl[2]), lstd_act(sl[3]));
    float4 lo1 = make_float4(lstd_act(sl[4]), lstd_act(sl[5]), lstd_act(sl[6]), lstd_act(sl[7]));
    float* om = out + (size_t)r * ACTD + c8;
    float* ol = out + (size_t)BB * ACTD + (size_t)r * ACTD + c8;
    *(float4*)(om)     = mo0;
    *(float4*)(om + 4) = mo1;
    *(float4*)(ol)     = lo0;
    *(float4*)(ol + 4) = lo1;
}

// -------------------------------------------------------------------------
// Tier B: fp32 expert-grouped GEMM (round-1, proven fallback).
// -------------------------------------------------------------------------
__global__ __launch_bounds__(256) void moe_gemm_f32(
    const float* __restrict__ x,
    const float* __restrict__ mean_w, const float* __restrict__ mean_b,
    const float* __restrict__ lstd_w, const float* __restrict__ lstd_b,
    const int* __restrict__ counts, const int* __restrict__ rowlist,
    const float* __restrict__ problist, float* __restrict__ out)
{
    const int e = blockIdx.y;
    const int cnt = counts[e];
    const int tile0 = blockIdx.x * 32;
    if (tile0 >= cnt) return;

    const int zz    = blockIdx.z;
    const int which = zz >> 1;
    const int ctile = (zz & 1) * 128;
    const float* W    = (which ? lstd_w : mean_w) + (size_t)e * ACTD * OBS;
    const float* bias = (which ? lstd_b : mean_b) + e * ACTD;
    float* outp = out + (size_t)which * BB * ACTD;

    __shared__ float xls[32][32];
    __shared__ float wls[32][128];

    const int sr  = threadIdx.x >> 3;
    const int skq = threadIdx.x & 7;
    int stage_row = -1;
    {
        const int pos = tile0 + sr;
        if (pos < cnt) stage_row = rowlist[e * BB + pos];
    }

    const int r0 = (threadIdx.x >> 5) << 2;
    const int c0 = (threadIdx.x & 31) << 2;

    float acc[4][4] = {};

    for (int kt = 0; kt < OBS; kt += 32) {
        __syncthreads();
        {
            float4 v = make_float4(0.f, 0.f, 0.f, 0.f);
            if (stage_row >= 0)
                v = *(const float4*)(x + (size_t)stage_row * OBS + kt + skq * 4);
            xls[skq * 4 + 0][sr] = v.x;
            xls[skq * 4 + 1][sr] = v.y;
            xls[skq * 4 + 2][sr] = v.z;
            xls[skq * 4 + 3][sr] = v.w;
        }
        #pragma unroll
        for (int j = 0; j < 4; ++j) {
            const int i  = threadIdx.x + 256 * j;
            const int c  = i >> 3;
            const int kq = i & 7;
            float4 v = *(const float4*)(W + (size_t)(ctile + c) * OBS + kt + kq * 4);
            wls[kq * 4 + 0][c] = v.x;
            wls[kq * 4 + 1][c] = v.y;
            wls[kq * 4 + 2][c] = v.z;
            wls[kq * 4 + 3][c] = v.w;
        }
        __syncthreads();

        #pragma unroll
        for (int k = 0; k < 32; ++k) {
            const float4 xa = *(const float4*)&xls[k][r0];
            const float4 wb = *(const float4*)&wls[k][c0];
            const float xv[4] = { xa.x, xa.y, xa.z, xa.w };
            const float wv[4] = { wb.x, wb.y, wb.z, wb.w };
            #pragma unroll
            for (int i = 0; i < 4; ++i)
                #pragma unroll
                for (int j = 0; j < 4; ++j)
                    acc[i][j] = fmaf(xv[i], wv[j], acc[i][j]);
        }
    }

    #pragma unroll
    for (int i = 0; i < 4; ++i) {
        const int pos = tile0 + r0 + i;
        if (pos >= cnt) break;
        const int grow = rowlist[e * BB + pos];
        const float pw = problist[e * BB + pos];
        float* orow = outp + (size_t)grow * ACTD + ctile + c0;
        #pragma unroll
        for (int j = 0; j < 4; ++j)
            atomicAdd(&orow[j], pw * (acc[i][j] + bias[ctile + c0 + j]));
    }
}

__global__ __launch_bounds__(256) void tanh_ep(float* __restrict__ out)
{
    const int i = blockIdx.x * 256 + threadIdx.x;
    float4* p = (float4*)(out + (size_t)BB * ACTD);
    float4 v = p[i];
    v.x = -5.f + 3.5f * (tanhf(v.x) + 1.f);
    v.y = -5.f + 3.5f * (tanhf(v.y) + 1.f);
    v.z = -5.f + 3.5f * (tanhf(v.z) + 1.f);
    v.w = -5.f + 3.5f * (tanhf(v.w) + 1.f);
    p[i] = v;
}

extern "C" void kernel_launch(void* const* d_in, const int* in_sizes, int n_in,
                              void* d_out, int out_size, void* d_ws, size_t ws_size,
                              hipStream_t stream)
{
    const float* x        = (const float*)d_in[0];
    const float* router_w = (const float*)d_in[1];
    const float* router_b = (const float*)d_in[2];
    const float* mean_w   = (const float*)d_in[3];
    const float* mean_b   = (const float*)d_in[4];
    const float* lstd_w   = (const float*)d_in[5];
    const float* lstd_b   = (const float*)d_in[6];

    float* out = (float*)d_out;
    int*    counts   = (int*)d_ws;
    int*    rowlist  = (int*)((char*)d_ws + WS_ROWLIST_OFF);
    float*  problist = (float*)((char*)d_ws + WS_PROBLIST_OFF);
    int*    slot_of  = (int*)((char*)d_ws + WS_SLOT_OFF);
    ushort* xbf      = (ushort*)((char*)d_ws + WS_XBF_OFF);
    ushort* wmbf     = (ushort*)((char*)d_ws + WS_WM_OFF);
    ushort* wlbf     = (ushort*)((char*)d_ws + WS_WL_OFF);
    ushort* partial  = (ushort*)((char*)d_ws + WS_PART_OFF);

    const bool tierA2 = (ws_size >= WS_NEEDED_A2);

    if (tierA2) {
        hipMemsetAsync(d_ws, 0, 64, stream);   // zero the 16 counters

        router_kernel<<<BB / 32, 256, 0, stream>>>(x, router_w, router_b,
                                                   counts, rowlist, problist,
                                                   slot_of, xbf,
                                                   mean_w, lstd_w, wmbf, wlbf, 1);

        dim3 grid(528, 4);
        moe_gemm_128<<<grid, 256, 0, stream>>>(xbf, wmbf, wlbf, mean_b, lstd_b,
                                               counts, rowlist, problist,
                                               slot_of, partial);
        combine_kernel<<<BB * 32 / 256, 256, 0, stream>>>(partial, out);
    } else {
        hipMemsetAsync(d_ws, 0, 64, stream);
        hipMemsetAsync(d_out, 0, (size_t)out_size * sizeof(float), stream);
        router_kernel<<<BB / 32, 256, 0, stream>>>(x, router_w, router_b,
                                                   counts, rowlist, problist,
                                                   (int*)nullptr, (ushort*)nullptr,
                                                   (const float*)nullptr,
                                                   (const float*)nullptr,
                                                   (ushort*)nullptr, (ushort*)nullptr, 0);
        dim3 grid(BB / 32, NE, 4);
        moe_gemm_f32<<<grid, 256, 0, stream>>>(x, mean_w, mean_b, lstd_w, lstd_b,
                                               counts, rowlist, problist, out);
        tanh_ep<<<(BB * ACTD / 4) / 256, 256, 0, stream>>>(out);
    }
}

// Round 12
// 188.596 us; speedup vs baseline: 1.1048x; 1.0148x over previous
//
#include <hip/hip_runtime.h>
#include <math.h>

#define BB   16384
#define OBS  512
#define NE   16
#define ACTD 256
#define TK   4

// ---------------- ws layout (proven ≥ 91 MB) ----------------
#define WS_ROWLIST_OFF  ((size_t)64)
#define WS_PROBLIST_OFF (WS_ROWLIST_OFF + (size_t)NE * BB * 4)
#define WS_SLOT_OFF     (WS_PROBLIST_OFF + (size_t)NE * BB * 4)
#define WS_XBF_OFF      (WS_SLOT_OFF + (size_t)NE * BB * 4)
#define WS_WM_OFF       (WS_XBF_OFF + (size_t)BB * OBS * 2)
#define WS_WL_OFF       (WS_WM_OFF + (size_t)NE * ACTD * OBS * 2)
#define WS_PART_OFF     (WS_WL_OFF + (size_t)NE * ACTD * OBS * 2)
#define WS_NEEDED_A2    (WS_PART_OFF + (size_t)2 * BB * TK * ACTD * 2)

typedef __attribute__((ext_vector_type(8))) short short8;
typedef __attribute__((ext_vector_type(4))) float floatx4;

__device__ __forceinline__ ushort f2bf(float f) {
    union { float f; unsigned u; } v; v.f = f;
    unsigned r = v.u + 0x7fffu + ((v.u >> 16) & 1u);
    return (ushort)(r >> 16);
}
__device__ __forceinline__ float bf2f(ushort u) {
    union { unsigned u; float f; } v; v.u = ((unsigned)u) << 16;
    return v.f;
}
// -5 + 3.5*(tanh(v)+1) == -5 + 7/(1+exp(-2v))
__device__ __forceinline__ float lstd_act(float v) {
    return -5.f + 7.f * __builtin_amdgcn_rcpf(1.f + __expf(-2.f * v));
}

// -------------------------------------------------------------------------
// Router v5: 16 rows/block (1024 blocks -> 4 blocks/CU TLP restored; v4's
// 512 blocks was 2/CU — grid-starved). Fused weight-cvt HOISTED BEFORE the
// routing math: issue wlds staging -> x loads -> xbf store -> cvt's 16
// float4 stream -> __syncthreads -> routing (regs+LDS only). The 96 MB of
// cvt traffic drains UNDER the routing compute (stores fire-and-forget)
// instead of serializing after the atomic/writeback tail: router ~=
// max(cvt, routing), not sum. Per-row math identical to proven v3.
// -------------------------------------------------------------------------
__global__ __launch_bounds__(256) void router_kernel(
    const float* __restrict__ x, const float* __restrict__ rw,
    const float* __restrict__ rb,
    int* __restrict__ counts, int* __restrict__ rowlist,
    float* __restrict__ problist, int* __restrict__ slot_of,
    ushort* __restrict__ xbf,
    const float* __restrict__ mwf, const float* __restrict__ lwf,
    ushort* __restrict__ wmbf, ushort* __restrict__ wlbf, int do_aux)
{
    __shared__ float wlds[NE * OBS];
    __shared__ int   lcnt[NE], lbase[NE];
    __shared__ int   s_e[64], s_lpos[64];
    __shared__ float s_p[64];

    // stage router weights -> LDS (consumed after the sync below)
    const float4* rw4 = (const float4*)rw;
    float4* wl4 = (float4*)wlds;
    #pragma unroll
    for (int i = 0; i < 8; ++i) wl4[threadIdx.x + 256 * i] = rw4[threadIdx.x + 256 * i];
    if (threadIdx.x < NE) lcnt[threadIdx.x] = 0;

    const int wave = threadIdx.x >> 6;
    const int lane = threadIdx.x & 63;
    const int q    = lane >> 4;
    const int i16  = lane & 15;
    const int row  = blockIdx.x * 16 + wave * 4 + q;

    // per-row x load (held in regs across the cvt phase)
    const float4* xr = (const float4*)(x + (size_t)row * OBS);
    float4 xv[8];
    #pragma unroll
    for (int s = 0; s < 8; ++s) xv[s] = xr[s * 16 + i16];

    if (do_aux) {
        ushort4* xo = (ushort4*)(xbf + (size_t)row * OBS);
        #pragma unroll
        for (int s = 0; s < 8; ++s) {
            ushort4 o;
            o.x = f2bf(xv[s].x); o.y = f2bf(xv[s].y);
            o.z = f2bf(xv[s].z); o.w = f2bf(xv[s].w);
            xo[s * 16 + i16] = o;
        }
        // ---- fused weight conversion, hoisted: overlaps routing below ----
        const int gid = blockIdx.x * 256 + threadIdx.x;     // 0..262143
        const float4* m4 = (const float4*)mwf;
        const float4* l4 = (const float4*)lwf;
        ushort4* mo = (ushort4*)wmbf;
        ushort4* lo = (ushort4*)wlbf;
        #pragma unroll
        for (int j = 0; j < 2; ++j) {
            const int idx = gid + 262144 * j;               // wn4 = 524288
            float4 a = m4[idx];
            ushort4 oa;
            oa.x = f2bf(a.x); oa.y = f2bf(a.y); oa.z = f2bf(a.z); oa.w = f2bf(a.w);
            mo[idx] = oa;
            float4 b = l4[idx];
            ushort4 ob;
            ob.x = f2bf(b.x); ob.y = f2bf(b.y); ob.z = f2bf(b.z); ob.w = f2bf(b.w);
            lo[idx] = ob;
        }
    }

    __syncthreads();   // wlds staged; cvt stores still draining (no wait)

    float p[NE];
    float m = -1e30f;
    #pragma unroll
    for (int e = 0; e < NE; ++e) {
        const float4* wep = (const float4*)(wlds + e * OBS);
        float d = 0.f;
        #pragma unroll
        for (int s = 0; s < 8; ++s) {
            float4 wv = wep[s * 16 + i16];
            d += xv[s].x * wv.x + xv[s].y * wv.y + xv[s].z * wv.z + xv[s].w * wv.w;
        }
        d += __shfl_xor(d, 1, 64);
        d += __shfl_xor(d, 2, 64);
        d += __shfl_xor(d, 4, 64);
        d += __shfl_xor(d, 8, 64);
        d += rb[e];
        p[e] = d;
        m = fmaxf(m, d);
    }
    float s = 0.f;
    #pragma unroll
    for (int e = 0; e < NE; ++e) { p[e] = __expf(p[e] - m); s += p[e]; }
    const float inv = 1.f / s;
    #pragma unroll
    for (int e = 0; e < NE; ++e) p[e] *= inv;

    int   sel_e[TK];
    float sel_p[TK];
    #pragma unroll
    for (int k = 0; k < TK; ++k) {
        float best = -1.f; int be = 0;
        #pragma unroll
        for (int e = 0; e < NE; ++e)
            if (p[e] > best) { best = p[e]; be = e; }
        sel_e[k] = be; sel_p[k] = best;
        #pragma unroll
        for (int e = 0; e < NE; ++e)
            if (e == be) p[e] = -2.f;
    }
    if (i16 < TK) {
        const int e = sel_e[i16];
        const int lpos = atomicAdd(&lcnt[e], 1);
        const int sid = (wave * 4 + q) * 4 + i16;
        s_e[sid] = e; s_p[sid] = sel_p[i16]; s_lpos[sid] = lpos;
    }
    __syncthreads();
    if (threadIdx.x < NE)
        lbase[threadIdx.x] = atomicAdd(&counts[threadIdx.x], lcnt[threadIdx.x]);
    __syncthreads();
    if (threadIdx.x < 64) {
        const int sid = threadIdx.x;
        const int e   = s_e[sid];
        const int pos = lbase[e] + s_lpos[sid];
        const int grow = blockIdx.x * 16 + (sid >> 2);
        rowlist[e * BB + pos]  = grow;
        problist[e * BB + pos] = s_p[sid];
        if (do_aux) slot_of[e * BB + pos] = grow * TK + (sid & 3);
    }
}

// -------------------------------------------------------------------------
// Expert-grouped bf16 MFMA GEMM — EXACT round-7 structure (proven local
// optimum): 128x128 tile, 4 waves of 64x64, single-buffer 33 KB LDS,
// 4 blocks/CU (reg-capped: 64 VGPR + 64 acc AGPR = 128/wave), compact
// tile space, XCD remap, conflict-free XOR swizzle, idx/probs LDS staging.
// r3/r5/r8/r10: at 8 K-steps/block, never trade co-resident blocks for
// per-block pipelining.
// -------------------------------------------------------------------------
__global__ __launch_bounds__(256, 4) void moe_gemm_128(
    const ushort* __restrict__ xbf,
    const ushort* __restrict__ wmean, const ushort* __restrict__ wlstd,
    const float* __restrict__ mean_b, const float* __restrict__ lstd_b,
    const int* __restrict__ counts, const int* __restrict__ rowlist,
    const float* __restrict__ problist, const int* __restrict__ slot_of,
    ushort* __restrict__ partial)
{
    const int flat = blockIdx.x + 528 * blockIdx.y;
    const int virt = (flat & 7) * 264 + (flat >> 3);
    const int zz   = virt & 3;
    const int gt   = virt >> 2;          // compact tile id 0..527

    // decode (expert, tile0) from compact tile id via counts prefix scan
    int e = -1, tile0 = 0, cnt = 0, tsum = 0;
    #pragma unroll
    for (int ee = 0; ee < NE; ++ee) {
        const int ce = counts[ee];
        const int nt = (ce + 127) >> 7;
        if (e < 0 && gt < tsum + nt) { e = ee; tile0 = (gt - tsum) * 128; cnt = ce; }
        tsum += nt;
    }
    if (e < 0) return;

    const int which = zz >> 1;
    const int ctile = (zz & 1) * 128;
    const ushort* W   = (which ? wlstd : wmean) + (size_t)e * ACTD * OBS;
    const float* bias = (which ? lstd_b : mean_b) + e * ACTD + ctile;
    ushort* Pp = partial + (size_t)which * BB * TK * ACTD;

    __shared__ __align__(16) ushort xls[128 * 64];   // 16 KB: 16 windows
    __shared__ __align__(16) ushort wls[128 * 64];   // 16 KB: 16 windows
    __shared__ int   idx_l[128];
    __shared__ float probs_l[128];

    const int tid = threadIdx.x;
    const int l   = tid & 63;
    const int w   = tid >> 6;

    if (tid < 128) {
        const int pos = tile0 + tid;
        const bool v = pos < cnt;
        probs_l[tid] = v ? problist[e * BB + pos] : 0.f;
        idx_l[tid]   = v ? slot_of[e * BB + pos] : -1;
    }

    const int c_sw = (l & 7) ^ (l >> 3);
    // x windows: wave w stages windows {4w..4w+3} (8 tile-rows each)
    const ushort* xp[4];
    #pragma unroll
    for (int i = 0; i < 4; ++i) {
        const int lrow = 32 * w + 8 * i + (l >> 3);
        const int pos  = tile0 + lrow;
        const int grow = (pos < cnt) ? rowlist[e * BB + pos] : rowlist[e * BB + tile0];
        xp[i] = xbf + (size_t)grow * OBS + c_sw * 8;
    }
    // W windows: wave w stages windows {4w..4w+3} (8 cols each)
    const ushort* wp[4];
    #pragma unroll
    for (int j = 0; j < 4; ++j) {
        const int col = ctile + 32 * w + 8 * j + (l >> 3);
        wp[j] = W + (size_t)col * OBS + c_sw * 8;
    }

    const int wm  = (w >> 1) * 64;   // row-half of 128
    const int wn  = (w & 1) * 64;    // col-half of 128
    const int rlo = l & 15;
    const int q   = l >> 4;
    const int r7  = rlo & 7;

    floatx4 acc[4][4];
    #pragma unroll
    for (int mi = 0; mi < 4; ++mi)
        #pragma unroll
        for (int ni = 0; ni < 4; ++ni)
            acc[mi][ni] = (floatx4){0.f, 0.f, 0.f, 0.f};

    for (int kt = 0; kt < OBS; kt += 64) {
        __syncthreads();
        #pragma unroll
        for (int i = 0; i < 4; ++i)
            __builtin_amdgcn_global_load_lds(
                (const __attribute__((address_space(1))) unsigned int*)(xp[i] + kt),
                (__attribute__((address_space(3))) unsigned int*)(xls + (4 * w + i) * 512),
                16, 0, 0);
        #pragma unroll
        for (int j = 0; j < 4; ++j)
            __builtin_amdgcn_global_load_lds(
                (const __attribute__((address_space(1))) unsigned int*)(wp[j] + kt),
                (__attribute__((address_space(3))) unsigned int*)(wls + (4 * w + j) * 512),
                16, 0, 0);
        __syncthreads();

        #pragma unroll
        for (int ks = 0; ks < 2; ++ks) {
            const int ch = (4 * ks + q) ^ r7;
            short8 af[4], bfr[4];
            #pragma unroll
            for (int mi = 0; mi < 4; ++mi)
                af[mi] = *(const short8*)(xls + (wm + mi * 16 + rlo) * 64 + ch * 8);
            #pragma unroll
            for (int ni = 0; ni < 4; ++ni)
                bfr[ni] = *(const short8*)(wls + (wn + ni * 16 + rlo) * 64 + ch * 8);
            #pragma unroll
            for (int mi = 0; mi < 4; ++mi)
                #pragma unroll
                for (int ni = 0; ni < 4; ++ni)
                    acc[mi][ni] = __builtin_amdgcn_mfma_f32_16x16x32_bf16(
                        af[mi], bfr[ni], acc[mi][ni], 0, 0, 0);
        }
    }

    #pragma unroll
    for (int mi = 0; mi < 4; ++mi) {
        #pragma unroll
        for (int r = 0; r < 4; ++r) {
            const int lrow = wm + mi * 16 + q * 4 + r;
            const int slot = idx_l[lrow];
            if (slot < 0) continue;
            const float pw = probs_l[lrow];
            ushort* orow = Pp + (size_t)slot * ACTD + ctile + wn + rlo;
            #pragma unroll
            for (int ni = 0; ni < 4; ++ni)
                orow[ni * 16] = f2bf(pw * (acc[mi][ni][r] + bias[wn + ni * 16 + rlo]));
        }
    }
}

// -------------------------------------------------------------------------
// Combine: out[r] = sum_k partial[r*4+k]; ushort8 (b128) loads.
// Thread handles 8 cols; grid = BB*32/256 = 2048 blocks.
// -------------------------------------------------------------------------
__global__ __launch_bounds__(256) void combine_kernel(
    const ushort* __restrict__ partial, float* __restrict__ out)
{
    const int t  = blockIdx.x * 256 + threadIdx.x;
    const int r  = t >> 5;
    const int c8 = (t & 31) * 8;
    const ushort* Pm = partial;
    const ushort* Pl = partial + (size_t)BB * TK * ACTD;

    float sm[8] = {}, sl[8] = {};
    #pragma unroll
    for (int k = 0; k < TK; ++k) {
        const size_t off = (size_t)(r * TK + k) * ACTD + c8;
        short8 vm = *(const short8*)(Pm + off);
        short8 vl = *(const short8*)(Pl + off);
        #pragma unroll
        for (int j = 0; j < 8; ++j) {
            sm[j] += bf2f((ushort)vm[j]);
            sl[j] += bf2f((ushort)vl[j]);
        }
    }
    float4 mo0 = make_float4(sm[0], sm[1], sm[2], sm[3]);
    float4 mo1 = make_float4(sm[4], sm[5], sm[6], sm[7]);
    float4 lo0 = make_float4(lstd_act(sl[0]), lstd_act(sl[1]), lstd_act(sl[2]), lstd_act(sl[3]));
    float4 lo1 = make_float4(lstd_act(sl[4]), lstd_act(sl[5]), lstd_act(sl[6]), lstd_act(sl[7]));
    float* om = out + (size_t)r * ACTD + c8;
    float* ol = out + (size_t)BB * ACTD + (size_t)r * ACTD + c8;
    *(float4*)(om)     = mo0;
    *(float4*)(om + 4) = mo1;
    *(float4*)(ol)     = lo0;
    *(float4*)(ol + 4) = lo1;
}

// -------------------------------------------------------------------------
// Tier B: fp32 expert-grouped GEMM (round-1, proven fallback).
// -------------------------------------------------------------------------
__global__ __launch_bounds__(256) void moe_gemm_f32(
    const float* __restrict__ x,
    const float* __restrict__ mean_w, const float* __restrict__ mean_b,
    const float* __restrict__ lstd_w, const float* __restrict__ lstd_b,
    const int* __restrict__ counts, const int* __restrict__ rowlist,
    const float* __restrict__ problist, float* __restrict__ out)
{
    const int e = blockIdx.y;
    const int cnt = counts[e];
    const int tile0 = blockIdx.x * 32;
    if (tile0 >= cnt) return;

    const int zz    = blockIdx.z;
    const int which = zz >> 1;
    const int ctile = (zz & 1) * 128;
    const float* W    = (which ? lstd_w : mean_w) + (size_t)e * ACTD * OBS;
    const float* bias = (which ? lstd_b : mean_b) + e * ACTD;
    float* outp = out + (size_t)which * BB * ACTD;

    __shared__ float xls[32][32];
    __shared__ float wls[32][128];

    const int sr  = threadIdx.x >> 3;
    const int skq = threadIdx.x & 7;
    int stage_row = -1;
    {
        const int pos = tile0 + sr;
        if (pos < cnt) stage_row = rowlist[e * BB + pos];
    }

    const int r0 = (threadIdx.x >> 5) << 2;
    const int c0 = (threadIdx.x & 31) << 2;

    float acc[4][4] = {};

    for (int kt = 0; kt < OBS; kt += 32) {
        __syncthreads();
        {
            float4 v = make_float4(0.f, 0.f, 0.f, 0.f);
            if (stage_row >= 0)
                v = *(const float4*)(x + (size_t)stage_row * OBS + kt + skq * 4);
            xls[skq * 4 + 0][sr] = v.x;
            xls[skq * 4 + 1][sr] = v.y;
            xls[skq * 4 + 2][sr] = v.z;
            xls[skq * 4 + 3][sr] = v.w;
        }
        #pragma unroll
        for (int j = 0; j < 4; ++j) {
            const int i  = threadIdx.x + 256 * j;
            const int c  = i >> 3;
            const int kq = i & 7;
            float4 v = *(const float4*)(W + (size_t)(ctile + c) * OBS + kt + kq * 4);
            wls[kq * 4 + 0][c] = v.x;
            wls[kq * 4 + 1][c] = v.y;
            wls[kq * 4 + 2][c] = v.z;
            wls[kq * 4 + 3][c] = v.w;
        }
        __syncthreads();

        #pragma unroll
        for (int k = 0; k < 32; ++k) {
            const float4 xa = *(const float4*)&xls[k][r0];
            const float4 wb = *(const float4*)&wls[k][c0];
            const float xv[4] = { xa.x, xa.y, xa.z, xa.w };
            const float wv[4] = { wb.x, wb.y, wb.z, wb.w };
            #pragma unroll
            for (int i = 0; i < 4; ++i)
                #pragma unroll
                for (int j = 0; j < 4; ++j)
                    acc[i][j] = fmaf(xv[i], wv[j], acc[i][j]);
        }
    }

    #pragma unroll
    for (int i = 0; i < 4; ++i) {
        const int pos = tile0 + r0 + i;
        if (pos >= cnt) break;
        const int grow = rowlist[e * BB + pos];
        const float pw = problist[e * BB + pos];
        float* orow = outp + (size_t)grow * ACTD + ctile + c0;
        #pragma unroll
        for (int j = 0; j < 4; ++j)
            atomicAdd(&orow[j], pw * (acc[i][j] + bias[ctile + c0 + j]));
    }
}

__global__ __launch_bounds__(256) void tanh_ep(float* __restrict__ out)
{
    const int i = blockIdx.x * 256 + threadIdx.x;
    float4* p = (float4*)(out + (size_t)BB * ACTD);
    float4 v = p[i];
    v.x = -5.f + 3.5f * (tanhf(v.x) + 1.f);
    v.y = -5.f + 3.5f * (tanhf(v.y) + 1.f);
    v.z = -5.f + 3.5f * (tanhf(v.z) + 1.f);
    v.w = -5.f + 3.5f * (tanhf(v.w) + 1.f);
    p[i] = v;
}

extern "C" void kernel_launch(void* const* d_in, const int* in_sizes, int n_in,
                              void* d_out, int out_size, void* d_ws, size_t ws_size,
                              hipStream_t stream)
{
    const float* x        = (const float*)d_in[0];
    const float* router_w = (const float*)d_in[1];
    const float* router_b = (const float*)d_in[2];
    const float* mean_w   = (const float*)d_in[3];
    const float* mean_b   = (const float*)d_in[4];
    const float* lstd_w   = (const float*)d_in[5];
    const float* lstd_b   = (const float*)d_in[6];

    float* out = (float*)d_out;
    int*    counts   = (int*)d_ws;
    int*    rowlist  = (int*)((char*)d_ws + WS_ROWLIST_OFF);
    float*  problist = (float*)((char*)d_ws + WS_PROBLIST_OFF);
    int*    slot_of  = (int*)((char*)d_ws + WS_SLOT_OFF);
    ushort* xbf      = (ushort*)((char*)d_ws + WS_XBF_OFF);
    ushort* wmbf     = (ushort*)((char*)d_ws + WS_WM_OFF);
    ushort* wlbf     = (ushort*)((char*)d_ws + WS_WL_OFF);
    ushort* partial  = (ushort*)((char*)d_ws + WS_PART_OFF);

    const bool tierA2 = (ws_size >= WS_NEEDED_A2);

    if (tierA2) {
        hipMemsetAsync(d_ws, 0, 64, stream);   // zero the 16 counters

        router_kernel<<<BB / 16, 256, 0, stream>>>(x, router_w, router_b,
                                                   counts, rowlist, problist,
                                                   slot_of, xbf,
                                                   mean_w, lstd_w, wmbf, wlbf, 1);

        dim3 grid(528, 4);
        moe_gemm_128<<<grid, 256, 0, stream>>>(xbf, wmbf, wlbf, mean_b, lstd_b,
                                               counts, rowlist, problist,
                                               slot_of, partial);
        combine_kernel<<<BB * 32 / 256, 256, 0, stream>>>(partial, out);
    } else {
        hipMemsetAsync(d_ws, 0, 64, stream);
        hipMemsetAsync(d_out, 0, (size_t)out_size * sizeof(float), stream);
        router_kernel<<<BB / 16, 256, 0, stream>>>(x, router_w, router_b,
                                                   counts, rowlist, problist,
                                                   (int*)nullptr, (ushort*)nullptr,
                                                   (const float*)nullptr,
                                                   (const float*)nullptr,
                                                   (ushort*)nullptr, (ushort*)nullptr, 0);
        dim3 grid(BB / 32, NE, 4);
        moe_gemm_f32<<<grid, 256, 0, stream>>>(x, mean_w, mean_b, lstd_w, lstd_b,
                                               counts, rowlist, problist, out);
        tanh_ep<<<(BB * ACTD / 4) / 256, 256, 0, stream>>>(out);
    }
}